// Round 1
// 1214.131 us; speedup vs baseline: 1.0005x; 1.0005x over previous
//
#include <hip/hip_runtime.h>
#include <cmath>

typedef unsigned short u16;
typedef unsigned int u32;

using bf16x8 = __attribute__((ext_vector_type(8))) __bf16;
using f32x4  = __attribute__((ext_vector_type(4))) float;

__device__ __forceinline__ u16 f2bf(float f) {
  union { float f; u32 i; } v; v.f = f;
  u32 u = v.i;
  return (u16)((u + 0x7FFFu + ((u >> 16) & 1u)) >> 16);
}

// load 8 fp32, convert to 8 bf16 packed in a uint4
__device__ __forceinline__ uint4 cvt8(const float* __restrict__ p) {
  float4 a = *(const float4*)p;
  float4 b = *(const float4*)(p + 4);
  union { u16 h[8]; uint4 v; } r;
  r.h[0] = f2bf(a.x); r.h[1] = f2bf(a.y); r.h[2] = f2bf(a.z); r.h[3] = f2bf(a.w);
  r.h[4] = f2bf(b.x); r.h[5] = f2bf(b.y); r.h[6] = f2bf(b.z); r.h[7] = f2bf(b.w);
  return r.v;
}
__device__ __forceinline__ uint4 cvt8s(const float* __restrict__ p, float s) {
  float4 a = *(const float4*)p;
  float4 b = *(const float4*)(p + 4);
  union { u16 h[8]; uint4 v; } r;
  r.h[0] = f2bf(a.x * s); r.h[1] = f2bf(a.y * s); r.h[2] = f2bf(a.z * s); r.h[3] = f2bf(a.w * s);
  r.h[4] = f2bf(b.x * s); r.h[5] = f2bf(b.y * s); r.h[6] = f2bf(b.z * s); r.h[7] = f2bf(b.w * s);
  return r.v;
}

#define LDS_STRIDE 72   // 64 + 8 pad: 2-way LDS conflict only (free)
#define HS_STRIDE  264  // 256 + 8 pad: same 2-way-only property (132 dwords % 32 == 4)

// ---------------------------------------------------------------------------
// Fused message kernel: per block, 16 rows of the 2048-row message batch.
// Phase 1: Htile(16x256) = relu(X(16x768) @ W1^T + b1), X gathered on the fly.
//   rows 0..1023  (side=src): X=[mem[src], mem[tgt], delta[b,src]]
//   rows 1024..2047 (side=tgt): X=[mem[tgt], mem[src], delta[b,tgt]]
// Phase 2: msg(16x256) = Htile @ W2^T + b2 -> atomicAdd scatter into sums;
//   counts once per row into cnt.
// grid 128, block 512 (8 waves: wave wv owns n-cols [wv*32, wv*32+32)).
// ---------------------------------------------------------------------------
__global__ __launch_bounds__(512) void k_msg_fused(
    const float* __restrict__ memory, const int* __restrict__ src,
    const int* __restrict__ tgt, const float* __restrict__ delta,
    const float* __restrict__ w1s, const float* __restrict__ b1s,
    const float* __restrict__ w2s, const float* __restrict__ b2s,
    const float* __restrict__ w1t, const float* __restrict__ b1t,
    const float* __restrict__ w2t, const float* __restrict__ b2t,
    float* __restrict__ sums, float* __restrict__ cnt) {
  __shared__ __align__(16) u16 As[16 * LDS_STRIDE];
  __shared__ __align__(16) u16 Bs[256 * LDS_STRIDE];
  __shared__ __align__(16) u16 Hs[16 * HS_STRIDE];
  const int m0 = blockIdx.x * 16;
  const int side = (m0 >= 1024);
  const float* __restrict__ W1 = side ? w1t : w1s;
  const float* __restrict__ B1 = side ? b1t : b1s;
  const float* __restrict__ W2 = side ? w2t : w2s;
  const float* __restrict__ B2 = side ? b2t : b2s;
  const int tid = threadIdx.x;
  const int wv = tid >> 6, lane = tid & 63, quad = lane >> 4, l16 = lane & 15;

  f32x4 acc[2];
#pragma unroll
  for (int i = 0; i < 2; ++i) acc[i] = (f32x4){0.f, 0.f, 0.f, 0.f};

  // ---------------- Phase 1: H = relu(X @ W1^T + b1) ----------------
  for (int kc = 0; kc < 768; kc += 64) {
    __syncthreads();
    // A tile: 16 rows x 64 k (gathered fp32 -> bf16). 128 chunks of 8.
    if (tid < 128) {
      int r = tid >> 3, c8 = (tid & 7) << 3;
      int k = kc + c8;
      int grow = m0 + r, b = grow & 1023;
      int ia = side ? tgt[b] : src[b];
      const float* p;
      int seg = k >> 8, kk = k & 255;
      if (seg == 0) {
        p = memory + ia * 256 + kk;
      } else if (seg == 1) {
        int ib = side ? src[b] : tgt[b];
        p = memory + ib * 256 + kk;
      } else {
        p = delta + ((size_t)(b * 1024 + ia)) * 256 + kk;
      }
      *(uint4*)&As[r * LDS_STRIDE + c8] = cvt8(p);
    }
    // B tile: all 256 n-rows x 64 k of W1 (row-major 256 x 768 fp32)
#pragma unroll
    for (int it = 0; it < 4; ++it) {
      int c2 = tid + it * 512;
      int r = c2 >> 3, c8 = (c2 & 7) << 3;
      *(uint4*)&Bs[r * LDS_STRIDE + c8] = cvt8(W1 + r * 768 + kc + c8);
    }
    __syncthreads();
#pragma unroll
    for (int ks = 0; ks < 64; ks += 32) {
      bf16x8 af = *(const bf16x8*)&As[l16 * LDS_STRIDE + ks + quad * 8];
#pragma unroll
      for (int nt = 0; nt < 2; ++nt) {
        bf16x8 bf = *(const bf16x8*)&Bs[(wv * 32 + nt * 16 + l16) * LDS_STRIDE + ks + quad * 8];
        acc[nt] = __builtin_amdgcn_mfma_f32_16x16x32_bf16(af, bf, acc[nt], 0, 0, 0);
      }
    }
  }
  // bias + relu -> Hs (bf16), reset acc for phase 2
#pragma unroll
  for (int nt = 0; nt < 2; ++nt) {
    int n = wv * 32 + nt * 16 + l16;
    float bias = B1[n];
#pragma unroll
    for (int r = 0; r < 4; ++r) {
      int m = quad * 4 + r;
      float v = acc[nt][r] + bias;
      Hs[m * HS_STRIDE + n] = f2bf(v > 0.f ? v : 0.f);
    }
    acc[nt] = (f32x4){0.f, 0.f, 0.f, 0.f};
  }

  // ---------------- Phase 2: msg = H @ W2^T + b2 ----------------
  for (int kc = 0; kc < 256; kc += 64) {
    __syncthreads();   // Hs writes visible; previous MFMA reads of Bs done
#pragma unroll
    for (int it = 0; it < 4; ++it) {
      int c2 = tid + it * 512;
      int r = c2 >> 3, c8 = (c2 & 7) << 3;
      *(uint4*)&Bs[r * LDS_STRIDE + c8] = cvt8(W2 + r * 256 + kc + c8);
    }
    __syncthreads();
#pragma unroll
    for (int ks = 0; ks < 64; ks += 32) {
      bf16x8 af = *(const bf16x8*)&Hs[l16 * HS_STRIDE + kc + ks + quad * 8];
#pragma unroll
      for (int nt = 0; nt < 2; ++nt) {
        bf16x8 bf = *(const bf16x8*)&Bs[(wv * 32 + nt * 16 + l16) * LDS_STRIDE + ks + quad * 8];
        acc[nt] = __builtin_amdgcn_mfma_f32_16x16x32_bf16(af, bf, acc[nt], 0, 0, 0);
      }
    }
  }
  // scatter into sums (+ counts once per row from wave 0 / l16==0)
#pragma unroll
  for (int nt = 0; nt < 2; ++nt) {
    int n = wv * 32 + nt * 16 + l16;
    float bias = B2[n];
#pragma unroll
    for (int r = 0; r < 4; ++r) {
      int m = quad * 4 + r;
      int grow = m0 + m, b = grow & 1023;
      int node = side ? tgt[b] : src[b];
      atomicAdd(&sums[node * 256 + n], acc[nt][r] + bias);
    }
  }
  if (wv == 0 && l16 == 0) {
#pragma unroll
    for (int r = 0; r < 4; ++r) {
      int grow = m0 + quad * 4 + r, b = grow & 1023;
      int node = side ? tgt[b] : src[b];
      atomicAdd(&cnt[node], 1.0f);
    }
  }
}

// ---------------------------------------------------------------------------
// K3: G[m, 0:768] = agg @ wih^T + bih ; G[m, 768:1536] = mem @ whh^T + bhh
// agg = sums/max(cnt,1) converted to bf16 at staging. grid (16,24). K=256.
// G is fp32.
// ---------------------------------------------------------------------------
__global__ __launch_bounds__(256) void k_gru_gemm(
    const float* __restrict__ sums, const float* __restrict__ cnt,
    const float* __restrict__ memory,
    const float* __restrict__ wih, const float* __restrict__ whh,
    const float* __restrict__ bih, const float* __restrict__ bhh,
    float* __restrict__ G) {
  __shared__ __align__(16) u16 As[64 * LDS_STRIDE];
  __shared__ __align__(16) u16 Bs[64 * LDS_STRIDE];
  const int m0 = blockIdx.x * 64;
  const int n0 = blockIdx.y * 64;
  const bool ghreg = (n0 >= 768);  // block fully in gi or gh region (768%64==0)
  const int tid = threadIdx.x;
  const int wv = tid >> 6, lane = tid & 63, quad = lane >> 4, l16 = lane & 15;

  f32x4 acc[4];
#pragma unroll
  for (int i = 0; i < 4; ++i) acc[i] = (f32x4){0.f, 0.f, 0.f, 0.f};

  for (int kc = 0; kc < 256; kc += 64) {
    __syncthreads();
#pragma unroll
    for (int it = 0; it < 2; ++it) {
      int c2 = tid + it * 256;
      int r = c2 >> 3, c8 = (c2 & 7) << 3;
      int k = kc + c8;
      int m = m0 + r;
      if (ghreg) {
        *(uint4*)&As[r * LDS_STRIDE + c8] = cvt8(memory + m * 256 + k);
      } else {
        float scale = 1.0f / fmaxf(cnt[m], 1.0f);
        *(uint4*)&As[r * LDS_STRIDE + c8] = cvt8s(sums + m * 256 + k, scale);
      }
      int ng = n0 + r;
      const float* Wr = (ng < 768) ? (wih + ng * 256) : (whh + (ng - 768) * 256);
      *(uint4*)&Bs[r * LDS_STRIDE + c8] = cvt8(Wr + k);
    }
    __syncthreads();
#pragma unroll
    for (int ks = 0; ks < 64; ks += 32) {
      bf16x8 af = *(const bf16x8*)&As[(wv * 16 + l16) * LDS_STRIDE + ks + quad * 8];
#pragma unroll
      for (int nt = 0; nt < 4; ++nt) {
        bf16x8 bf = *(const bf16x8*)&Bs[(nt * 16 + l16) * LDS_STRIDE + ks + quad * 8];
        acc[nt] = __builtin_amdgcn_mfma_f32_16x16x32_bf16(af, bf, acc[nt], 0, 0, 0);
      }
    }
  }
#pragma unroll
  for (int nt = 0; nt < 4; ++nt) {
    int ng = n0 + nt * 16 + l16;
    float bias = (ng < 768) ? bih[ng] : bhh[ng - 768];
#pragma unroll
    for (int r = 0; r < 4; ++r) {
      int m = m0 + wv * 16 + quad * 4 + r;
      G[m * 1536 + ng] = acc[nt][r] + bias;
    }
  }
}

// ---------------------------------------------------------------------------
// K4: GRU gates + touched-select, write fp32 output (1024 x 256).
// Untouched rows copy memory exactly.
// ---------------------------------------------------------------------------
__global__ __launch_bounds__(256) void k_gru_epi(
    const float* __restrict__ G, const float* __restrict__ cnt,
    const float* __restrict__ memory, float* __restrict__ out) {
  int gid = blockIdx.x * 256 + threadIdx.x;  // 0..262143
  int m = gid >> 8, d = gid & 255;
  const float* g = G + m * 1536;
  float ir = g[d], iz = g[256 + d], in_ = g[512 + d];
  float hr = g[768 + d], hz = g[1024 + d], hn = g[1280 + d];
  float r = 1.f / (1.f + expf(-(ir + hr)));
  float z = 1.f / (1.f + expf(-(iz + hz)));
  float nn = tanhf(in_ + r * hn);
  float h = memory[gid];
  float nv = (1.f - z) * nn + z * h;
  out[gid] = (cnt[m] > 0.f) ? nv : h;
}

// ---------------------------------------------------------------------------
extern "C" void kernel_launch(void* const* d_in, const int* in_sizes, int n_in,
                              void* d_out, int out_size, void* d_ws, size_t ws_size,
                              hipStream_t stream) {
  const float* memory = (const float*)d_in[0];
  const int*   src    = (const int*)d_in[1];
  const int*   tgt    = (const int*)d_in[2];
  const float* delta  = (const float*)d_in[3];
  const float* w1s = (const float*)d_in[4];
  const float* b1s = (const float*)d_in[5];
  const float* w2s = (const float*)d_in[6];
  const float* b2s = (const float*)d_in[7];
  const float* w1t = (const float*)d_in[8];
  const float* b1t = (const float*)d_in[9];
  const float* w2t = (const float*)d_in[10];
  const float* b2t = (const float*)d_in[11];
  const float* wih = (const float*)d_in[12];
  const float* whh = (const float*)d_in[13];
  const float* bih = (const float*)d_in[14];
  const float* bhh = (const float*)d_in[15];

  char* ws = (char*)d_ws;
  float* sums = (float*)ws;                       // 1024*256*4 = 1048576 B
  float* cnt  = (float*)(ws + 1048576);           // 1024*4 -> pad to 4096 B
  float* G    = (float*)(ws + 1052672);           // 1024*1536*4 = 6291456 B

  hipMemsetAsync(ws, 0, 1052672, stream);  // zero sums + cnt

  k_msg_fused<<<dim3(128), 512, 0, stream>>>(memory, src, tgt, delta,
                                             w1s, b1s, w2s, b2s,
                                             w1t, b1t, w2t, b2t, sums, cnt);
  k_gru_gemm<<<dim3(16, 24), 256, 0, stream>>>(sums, cnt, memory,
                                               wih, whh, bih, bhh, G);
  k_gru_epi<<<1024, 256, 0, stream>>>(G, cnt, memory, (float*)d_out);
}